// Round 7
// baseline (368.903 us; speedup 1.0000x reference)
//
#include <hip/hip_runtime.h>

#define IMG_H 512
#define IMG_W 512
#define CH_STRIDE (IMG_H*IMG_W)     // 262144
#define IMG_STRIDE (3*CH_STRIDE)

using f2    = __attribute__((ext_vector_type(2))) float;
using f4    = __attribute__((ext_vector_type(4))) float;
using h2    = __attribute__((ext_vector_type(2))) _Float16;
using h4    = __attribute__((ext_vector_type(4))) _Float16;
using h8    = __attribute__((ext_vector_type(8))) _Float16;
using f32x4 = __attribute__((ext_vector_type(4))) float;

// acc: 64 slots x 32 floats: 0=con 1=gx 2=gy 3=cb 4=cr 5=ssim_rgb 6=ssim_ir
// ws layout: [0,8KB) acc slots; [8KB,10KB) 64-lane weight-frag table
#define NSLOT 64
#define SLOT_F 32
#define WTAB_OFF 8192

__global__ __launch_bounds__(256) void k_zero(float* __restrict__ acc) {
  int i = threadIdx.x;
  *(f4*)&acc[i*8]     = f4{0,0,0,0};
  *(f4*)&acc[i*8 + 4] = f4{0,0,0,0};
  // weight fragment table: lane l holds Wh/Wv B-frags for MFMA convs
  // w(d)=exp(-d^2/4.5)/3.759232795; Wh[k][x]=g[k-x-3], Wv[k][y]=g[k-y]
  if (i < 64) {
    int lr = i & 15, lg = (i >> 4) & 3;
    h8 bh, bv;
    #pragma unroll
    for (int e = 0; e < 8; ++e) {
      int k = lg*8 + e;
      int jh = k - lr - 3;
      int jv = k - lr;
      float wh = 0.f, wvv = 0.f;
      if ((unsigned)jh < 11u) {
        float d = (float)(jh - 5);
        wh = exp2f(-d*d*0.32059889798f) * 0.26601255681f;
      }
      if ((unsigned)jv < 11u) {
        float d = (float)(jv - 5);
        wvv = exp2f(-d*d*0.32059889798f) * 0.26601255681f;
      }
      bh[e] = (_Float16)wh;
      bv[e] = (_Float16)wvv;
    }
    char* wt = (char*)acc + WTAB_OFF + i*32;
    *(h8*)wt        = bh;
    *(h8*)(wt + 16) = bv;
  }
}

__device__ __forceinline__ h4 cvt4(f4 v) {
  h2 lo = __builtin_bit_cast(h2, __builtin_amdgcn_cvt_pkrtz(v.x, v.y));
  h2 hi = __builtin_bit_cast(h2, __builtin_amdgcn_cvt_pkrtz(v.z, v.w));
  return h4{lo[0], lo[1], hi[0], hi[1]};
}
__device__ __forceinline__ h4 pk4(f32x4 d) {
  h2 lo = __builtin_bit_cast(h2, __builtin_amdgcn_cvt_pkrtz(d[0], d[1]));
  h2 hi = __builtin_bit_cast(h2, __builtin_amdgcn_cvt_pkrtz(d[2], d[3]));
  return h4{lo[0], lo[1], hi[0], hi[1]};
}
__device__ __forceinline__ h8 zero8() {
  return h8{(_Float16)0,(_Float16)0,(_Float16)0,(_Float16)0,
            (_Float16)0,(_Float16)0,(_Float16)0,(_Float16)0};
}

// ---- sobel geometry: tile 64x16, halo 1; LDS row stride 68 floats -------
#define R1W 68
#define R1N (18*R1W)   // 1224 floats per field

// ---- SSIM MFMA geometry (offsets in _Float16 units) ----------------------
// staged: 2 fields (A=x, B=y), 26 rows x 80 cols used, stride 88 (bank-free)
// hbT:    4 fields x 64 px x 32 k, XOR-swizzled 16B granules
#define SXW 88
#define SXH 26
#define SF_STRIDE (SXH*SXW)          // 2288 halves per field
#define HB_OFF    (2*SF_STRIDE)      // 4576
#define HB_F      (64*32)            // 2048 halves per field
#define SMEM_H    (HB_OFF + 4*HB_F)  // 12768 halves
#define SMEM_BYTES (SMEM_H*2 + 128)  // 25664 bytes (sobel needs 14688)

// ---- Phase B: horizontal conv via MFMA; wave = x-tile ---------------------
__device__ __forceinline__ void phaseB(_Float16* S, h8 bh,
                                       int lr, int lg, int xo) {
  const int px = xo + lr;
  const int sgrp = (px ^ (px >> 2)) & 3;            // bank swizzle key
  #pragma unroll
  for (int rt = 0; rt < 2; ++rt) {
    int row_s = rt*16 + lr;
    int rcl = row_s > 25 ? 25 : row_s;
    int rbase = rcl*SXW + xo + lg*8;
    h8 a = *(const h8*)&S[rbase];
    h8 b = *(const h8*)&S[SF_STRIDE + rbase];
    if (row_s > 25) { a = zero8(); b = zero8(); }
    h8 p = a*a + b*b;
    h8 q = a*b;
    f32x4 d0 = __builtin_amdgcn_mfma_f32_16x16x32_f16(
                   a, bh, f32x4{0.f,0.f,0.f,0.f}, 0, 0, 0);
    f32x4 d1 = __builtin_amdgcn_mfma_f32_16x16x32_f16(
                   b, bh, f32x4{0.f,0.f,0.f,0.f}, 0, 0, 0);
    f32x4 d2 = __builtin_amdgcn_mfma_f32_16x16x32_f16(
                   p, bh, f32x4{0.f,0.f,0.f,0.f}, 0, 0, 0);
    f32x4 d3 = __builtin_amdgcn_mfma_f32_16x16x32_f16(
                   q, bh, f32x4{0.f,0.f,0.f,0.f}, 0, 0, 0);
    int k0 = rt*16 + lg*4;
    int bb2 = k0 << 1;                              // byte in 64B row
    int sbk = ((((bb2 >> 4) ^ sgrp) << 4) | (bb2 & 15));
    int base = HB_OFF + px*32 + (sbk >> 1);
    *(h4*)&S[base + 0*HB_F] = pk4(d0);
    *(h4*)&S[base + 1*HB_F] = pk4(d1);
    *(h4*)&S[base + 2*HB_F] = pk4(d2);
    *(h4*)&S[base + 3*HB_F] = pk4(d3);
  }
}

// ---- Phase C: vertical conv via MFMA + SSIM epilogue ----------------------
__device__ __forceinline__ float phaseC(const _Float16* S, h8 bv,
                                        int lr, int lg, int xo) {
  const int pxA = xo + lr;
  const int sgrp = (pxA ^ (pxA >> 2)) & 3;
  const int gi = lg ^ sgrp;
  f32x4 dd[4];
  #pragma unroll
  for (int f = 0; f < 4; ++f) {
    h8 a = *(const h8*)&S[HB_OFF + f*HB_F + pxA*32 + gi*8];
    dd[f] = __builtin_amdgcn_mfma_f32_16x16x32_f16(
                a, bv, f32x4{0.f,0.f,0.f,0.f}, 0, 0, 0);
  }
  float ss = 0.f;
  #pragma unroll
  for (int r2 = 0; r2 < 4; ++r2) {
    float mu1 = dd[0][r2], mu2 = dd[1][r2];
    float sP  = dd[2][r2], sQ  = dd[3][r2];
    float mu12 = mu1*mu2, mss = mu1*mu1 + mu2*mu2;
    float s12 = sQ - mu12, sps = sP - mss;
    float num = (2.f*mu12 + 1e-4f)*(2.f*s12 + 9e-4f);
    float den = (mss + 1e-4f)*(sps + 9e-4f);
    ss += num * __builtin_amdgcn_rcpf(den);   // <=1ulp, ~1e-7 on ~1.0 ratio
  }
  return ss;
}

__global__ __launch_bounds__(256, 6) void k_main(
    const float* __restrict__ vis, const float* __restrict__ ir,
    const float* __restrict__ fuse, float* __restrict__ acc)
{
  __shared__ __align__(16) char smem[SMEM_BYTES];
  float* red = (float*)(smem + SMEM_H*2);   // 32 floats scratch
  const int tid = threadIdx.x;
  const int bid = blockIdx.x;
  float* aslot = acc + (bid & (NSLOT-1))*SLOT_F;

  // interleave: every 3rd block is sobel (8192 SSIM + 4096 sobel = 12288)
  const int sb = bid / 3;
  const int rm = bid - sb*3;

  if (rm < 2) {
    // ======== SSIM superblock: two stacked 64x16 tiles, pipelined ========
    const int si = sb*2 + rm;           // 0..8191
    const int z = si >> 7;              // n*4 + pair
    const int n = z >> 2, pair = z & 3;
    const int x0 = (si & 7)*64;
    const int y0a = ((si >> 3) & 15)*32;
    const int y0b = y0a + 16;
    _Float16* S = (_Float16*)smem;

    const int lr = tid & 15;          // frag row/col within 16
    const int lg = (tid >> 4) & 3;    // frag k-group
    const int wvw = tid >> 6;         // wave id 0..3
    const int xo = wvw*16;

    const float* xb;
    const float* yb;
    if (pair < 3) {
      xb = vis  + (n*3 + pair)*CH_STRIDE;
      yb = fuse + (n*3 + pair)*CH_STRIDE;
    } else {
      xb = ir   + n*IMG_STRIDE;
      yb = fuse + n*IMG_STRIDE;
    }

    // ---- Gaussian weight fragments from precomputed table ----
    h8 bh, bv;
    {
      const char* wt = (const char*)acc + WTAB_OFF + (tid & 63)*32;
      bh = *(const h8*)wt;
      bv = *(const h8*)(wt + 16);
    }

    // staging task split: 520 tasks, iters {tid, tid+256, tid+512(tid<8)}
    const int row0 = tid / 20,        k0c = tid - row0*20;
    const int i1r  = tid + 256;
    const int row1 = i1r / 20,        k1c = i1r - row1*20;

    // ---- stage tile0 (synchronous) ----
    if (pair < 3) {
      for (int i = tid; i < SXH*20; i += 256) {
        int row = i / 20, k = i - row*20;
        int gy = y0a - 5 + row, gx = x0 - 8 + 4*k;
        f4 xv = {0,0,0,0}, yv = {0,0,0,0};
        if ((unsigned)gy < IMG_H && (unsigned)gx < IMG_W) {
          int off = gy*IMG_W + gx;
          xv = *(const f4*)&xb[off];
          yv = *(const f4*)&yb[off];
        }
        int ib = row*SXW + 4*k;
        *(h4*)&S[ib]             = cvt4(xv);
        *(h4*)&S[SF_STRIDE + ib] = cvt4(yv);
      }
    } else {
      for (int i = tid; i < SXH*20; i += 256) {
        int row = i / 20, k = i - row*20;
        int gy = y0a - 5 + row, gx = x0 - 8 + 4*k;
        f4 xv = {0,0,0,0}, yv = {0,0,0,0};
        if ((unsigned)gy < IMG_H && (unsigned)gx < IMG_W) {
          int off = gy*IMG_W + gx;
          xv = *(const f4*)&xb[off];
          f4 rr = *(const f4*)&yb[off];
          f4 gg = *(const f4*)&yb[off + CH_STRIDE];
          f4 bb = *(const f4*)&yb[off + 2*CH_STRIDE];
          #pragma unroll
          for (int j = 0; j < 4; ++j)
            yv[j] = 0.2989f*rr[j] + 0.587f*gg[j] + 0.114f*bb[j];
        }
        int ib = row*SXW + 4*k;
        *(h4*)&S[ib]             = cvt4(xv);
        *(h4*)&S[SF_STRIDE + ib] = cvt4(yv);
      }
    }
    __syncthreads();                                 // bar A

    // ---- issue tile1 prefetch loads (iters 0,1) into registers ----
    f4 p0x = {0,0,0,0}, p0y = {0,0,0,0}, p1x = {0,0,0,0}, p1y = {0,0,0,0};
    f4 q0g = {0,0,0,0}, q0b = {0,0,0,0}, q1g = {0,0,0,0}, q1b = {0,0,0,0};
    {
      int gy0 = y0b - 5 + row0, gx0 = x0 - 8 + 4*k0c;
      int gy1 = y0b - 5 + row1, gx1 = x0 - 8 + 4*k1c;
      bool v0 = (unsigned)gy0 < IMG_H && (unsigned)gx0 < IMG_W;
      bool v1 = (unsigned)gy1 < IMG_H && (unsigned)gx1 < IMG_W;
      int o0 = gy0*IMG_W + gx0, o1 = gy1*IMG_W + gx1;
      if (pair < 3) {
        if (v0) { p0x = *(const f4*)&xb[o0]; p0y = *(const f4*)&yb[o0]; }
        if (v1) { p1x = *(const f4*)&xb[o1]; p1y = *(const f4*)&yb[o1]; }
      } else {
        if (v0) {
          p0x = *(const f4*)&xb[o0];
          p0y = *(const f4*)&yb[o0];
          q0g = *(const f4*)&yb[o0 + CH_STRIDE];
          q0b = *(const f4*)&yb[o0 + 2*CH_STRIDE];
        }
        if (v1) {
          p1x = *(const f4*)&xb[o1];
          p1y = *(const f4*)&yb[o1];
          q1g = *(const f4*)&yb[o1 + CH_STRIDE];
          q1b = *(const f4*)&yb[o1 + 2*CH_STRIDE];
        }
      }
    }

    phaseB(S, bh, lr, lg, xo);                       // tile0 horizontal
    __syncthreads();                                 // bar B

    // ---- commit tile1 staged data (regs -> LDS) ----
    {
      int ib0 = row0*SXW + 4*k0c;
      int ib1 = row1*SXW + 4*k1c;
      if (pair < 3) {
        *(h4*)&S[ib0]             = cvt4(p0x);
        *(h4*)&S[SF_STRIDE + ib0] = cvt4(p0y);
        *(h4*)&S[ib1]             = cvt4(p1x);
        *(h4*)&S[SF_STRIDE + ib1] = cvt4(p1y);
      } else {
        f4 l0, l1;
        #pragma unroll
        for (int j = 0; j < 4; ++j) {
          l0[j] = 0.2989f*p0y[j] + 0.587f*q0g[j] + 0.114f*q0b[j];
          l1[j] = 0.2989f*p1y[j] + 0.587f*q1g[j] + 0.114f*q1b[j];
        }
        *(h4*)&S[ib0]             = cvt4(p0x);
        *(h4*)&S[SF_STRIDE + ib0] = cvt4(l0);
        *(h4*)&S[ib1]             = cvt4(p1x);
        *(h4*)&S[SF_STRIDE + ib1] = cvt4(l1);
      }
      if (tid < 8) {                                 // iter2 tail (8 threads)
        int k2 = tid + 12;                           // row 25
        int gy2 = y0b + 20, gx2 = x0 - 8 + 4*k2;
        f4 xv = {0,0,0,0}, yv = {0,0,0,0};
        if ((unsigned)gy2 < IMG_H && (unsigned)gx2 < IMG_W) {
          int off = gy2*IMG_W + gx2;
          xv = *(const f4*)&xb[off];
          if (pair < 3) yv = *(const f4*)&yb[off];
          else {
            f4 rr = *(const f4*)&yb[off];
            f4 gg = *(const f4*)&yb[off + CH_STRIDE];
            f4 bb = *(const f4*)&yb[off + 2*CH_STRIDE];
            #pragma unroll
            for (int j = 0; j < 4; ++j)
              yv[j] = 0.2989f*rr[j] + 0.587f*gg[j] + 0.114f*bb[j];
          }
        }
        int ib2 = 25*SXW + 4*k2;
        *(h4*)&S[ib2]             = cvt4(xv);
        *(h4*)&S[SF_STRIDE + ib2] = cvt4(yv);
      }
    }

    float ss = phaseC(S, bv, lr, lg, xo);            // tile0 vertical+epilog
    __syncthreads();                                 // bar C
    phaseB(S, bh, lr, lg, xo);                       // tile1 horizontal
    __syncthreads();                                 // bar D
    ss += phaseC(S, bv, lr, lg, xo);                 // tile1 vertical+epilog

    #pragma unroll
    for (int o = 32; o > 0; o >>= 1) ss += __shfl_down(ss, o, 64);
    if ((tid & 63) == 0) atomicAdd(&aslot[(pair == 3) ? 6 : 5], ss);

  } else {
    // ========== point + sobel + color block (pipelined channels) =========
    const int r = sb;                    // 0..4095
    const int x0 = (r & 7)*64;
    const int y0 = ((r >> 3) & 31)*16;
    const int n  = r >> 8;
    float* s = (float*)smem;   // 3 fields x 1224 floats (14.7 KB)
    const int ox = (tid & 15)*4;
    const int oy = tid >> 4;

    const float* visB  = vis  + n*IMG_STRIDE;
    const float* irB   = ir   + n*IMG_STRIDE;
    const float* fuseB = fuse + n*IMG_STRIDE;

    // ---- precompute staging tasks once (reused for all 3 channels) ------
    // interior: 864 f4-groups = 3 fields x 18 rows x 16; iters tid+it*256
    int  ioff[4], idst[4];
    bool iact[4], ival[4];
    const float* ibase[4];
    #pragma unroll
    for (int it = 0; it < 4; ++it) {
      int i = tid + it*256;
      iact[it] = i < 864;
      int ic = iact[it] ? i : 0;
      int f = ic / 288;
      int rr = ic - f*288;
      int row = rr >> 4, k = rr & 15;
      int gy = y0 - 1 + row, gx = x0 + 4*k;
      ival[it] = iact[it] && ((unsigned)gy < IMG_H);
      ioff[it] = gy*IMG_W + gx;
      idst[it] = f*R1N + row*R1W + 1 + 4*k;
      ibase[it] = (f == 0) ? visB : ((f == 1) ? irB : fuseB);
    }
    // edges: 108 scalars = 3 fields x 18 rows x 2
    const bool eAct = tid < 108;
    int eoff = 0, edst = 0; bool eVal = false; const float* eBase = visB;
    {
      int tc = eAct ? tid : 0;
      int f = tc / 36;
      int rr = tc - f*36;
      int row = rr >> 1, side = rr & 1;
      int gy = y0 - 1 + row;
      int gx = side ? (x0 + 64) : (x0 - 1);
      eVal = eAct && ((unsigned)gx < IMG_W) && ((unsigned)gy < IMG_H);
      eoff = gy*IMG_W + gx;
      edst = f*R1N + row*R1W + (side ? 65 : 0);
      eBase = (f == 0) ? visB : ((f == 1) ? irB : fuseB);
    }

    // ---- load channel 0 into regs ----
    f4 pre[4]; float preE = 0.f;
    #pragma unroll
    for (int it = 0; it < 4; ++it) {
      pre[it] = f4{0,0,0,0};
      if (ival[it]) pre[it] = *(const f4*)&ibase[it][ioff[it]];
    }
    if (eVal) preE = eBase[eoff];

    float con=0.f, gxs=0.f, gys=0.f, cbs=0.f, crs=0.f;
    float pv0[4], pv2[4], pf0[4], pf2[4], Yv[4], Yf[4];
    #pragma unroll
    for (int j = 0; j < 4; ++j) { Yv[j]=0.f; Yf[j]=0.f; }

    for (int c = 0; c < 3; ++c) {
      // commit channel c regs -> LDS
      #pragma unroll
      for (int it = 0; it < 4; ++it)
        if (iact[it]) *(f4*)&s[idst[it]] = pre[it];
      if (eAct) s[edst] = preE;
      __syncthreads();

      // issue channel c+1 loads (in flight across compute below)
      if (c < 2) {
        int co = (c + 1)*CH_STRIDE;
        #pragma unroll
        for (int it = 0; it < 4; ++it) {
          pre[it] = f4{0,0,0,0};
          if (ival[it]) pre[it] = *(const f4*)&ibase[it][co + ioff[it]];
        }
        preE = 0.f;
        if (eVal) preE = eBase[co + eoff];
      }

      // compute channel c (separable sobel from LDS)
      const float yc = (c == 0) ? 0.299f : ((c == 1) ? 0.587f : 0.114f);
      float cen[3][4], gxv[3][4], gyv[3][4];
      #pragma unroll
      for (int t = 0; t < 3; ++t) {
        const float* sf = s + t*R1N + oy*R1W + ox;
        f4 a0 = *(const f4*)&sf[0];
        f2 b0 = *(const f2*)&sf[4];
        f4 a1 = *(const f4*)&sf[R1W];
        f2 b1 = *(const f2*)&sf[R1W + 4];
        f4 a2 = *(const f4*)&sf[2*R1W];
        f2 b2 = *(const f2*)&sf[2*R1W + 4];
        float r0[6] = {a0.x,a0.y,a0.z,a0.w,b0.x,b0.y};
        float r1[6] = {a1.x,a1.y,a1.z,a1.w,b1.x,b1.y};
        float r2[6] = {a2.x,a2.y,a2.z,a2.w,b2.x,b2.y};
        float ty[6], dy[6];
        #pragma unroll
        for (int x = 0; x < 6; ++x) {
          ty[x] = r0[x] + 2.f*r1[x] + r2[x];   // smooth_y
          dy[x] = r0[x] - r2[x];               // diff_y
        }
        #pragma unroll
        for (int j = 0; j < 4; ++j) {
          gxv[t][j] = ty[j+2] - ty[j];                    // diff_x(smooth_y)
          gyv[t][j] = dy[j] + 2.f*dy[j+1] + dy[j+2];      // smooth_x(diff_y)
          cen[t][j] = r1[j+1];
        }
      }
      #pragma unroll
      for (int j = 0; j < 4; ++j) {
        con += fabsf(cen[2][j] - fmaxf(cen[0][j], cen[1][j]));
        gxs += fabsf(gxv[2][j] - fmaxf(gxv[0][j], gxv[1][j]));
        gys += fabsf(gyv[2][j] - fmaxf(gyv[0][j], gyv[1][j]));
        Yv[j] += yc*cen[0][j];
        Yf[j] += yc*cen[2][j];
        if (c == 0) { pv0[j] = cen[0][j]; pf0[j] = cen[2][j]; }
        if (c == 2) { pv2[j] = cen[0][j]; pf2[j] = cen[2][j]; }
      }
      __syncthreads();   // WAR guard before restaging
    }

    #pragma unroll
    for (int j = 0; j < 4; ++j) {
      crs += fabsf(0.713f*((pf0[j]-Yf[j]) - (pv0[j]-Yv[j])));
      cbs += fabsf(0.564f*((pf2[j]-Yf[j]) - (pv2[j]-Yv[j])));
    }

    // wave reduce 5 sums -> LDS -> 1 barrier -> 5 atomics
    float sums[5] = {con, gxs, gys, cbs, crs};
    const int lane = tid & 63, wvw2 = tid >> 6;
    #pragma unroll
    for (int i2 = 0; i2 < 5; ++i2) {
      float v = sums[i2];
      #pragma unroll
      for (int o = 32; o > 0; o >>= 1) v += __shfl_down(v, o, 64);
      if (lane == 0) red[wvw2*5 + i2] = v;
    }
    __syncthreads();
    if (tid < 5)
      atomicAdd(&aslot[tid], red[tid] + red[5+tid] + red[10+tid] + red[15+tid]);
  }
}

// ---------------- final combine: one wave over 64 slots -------------------
__global__ __launch_bounds__(64) void k_final(
    const float* __restrict__ acc, float* __restrict__ out)
{
  int lane = threadIdx.x;
  float s[7];
  #pragma unroll
  for (int c = 0; c < 7; ++c) {
    float x = acc[lane*SLOT_F + c];
    #pragma unroll
    for (int o = 32; o > 0; o >>= 1) x += __shfl_down(x, o, 64);
    s[c] = x;
  }
  if (lane == 0) {
    const float N3 = 16.f*3.f*512.f*512.f;
    const float N1 = 16.f*512.f*512.f;
    float con_loss  = s[0] / N3;
    float grad_loss = 0.5f*(s[1]/N3) + 0.5f*(s[2]/N3);
    float color_loss = s[3]/N1 + s[4]/N1;
    float ssim_loss = 1.f - (s[5]/N3 + s[6]/N1)*0.5f;
    out[0] = 0.5f*con_loss + 0.2f*grad_loss + color_loss + 0.1f*ssim_loss;
  }
}

extern "C" void kernel_launch(void* const* d_in, const int* in_sizes, int n_in,
                              void* d_out, int out_size, void* d_ws, size_t ws_size,
                              hipStream_t stream) {
  (void)in_sizes; (void)n_in; (void)out_size; (void)ws_size;
  const float* vis  = (const float*)d_in[0];
  const float* ir   = (const float*)d_in[1];
  const float* fuse = (const float*)d_in[2];
  float* out = (float*)d_out;
  float* acc = (float*)d_ws;   // 8 KB slots + 2 KB weight table

  k_zero<<<dim3(1,1,1), dim3(256,1,1), 0, stream>>>(acc);
  k_main<<<dim3(12288,1,1), dim3(256,1,1), 0, stream>>>(vis, ir, fuse, acc);
  k_final<<<dim3(1,1,1), dim3(64,1,1), 0, stream>>>(acc, out);
}

// Round 8
// 208.883 us; speedup vs baseline: 1.7661x; 1.7661x over previous
//
#include <hip/hip_runtime.h>

#define IMG_H 512
#define IMG_W 512
#define CH_STRIDE (IMG_H*IMG_W)     // 262144
#define IMG_STRIDE (3*CH_STRIDE)

using f2    = __attribute__((ext_vector_type(2))) float;
using f4    = __attribute__((ext_vector_type(4))) float;
using h2    = __attribute__((ext_vector_type(2))) _Float16;
using h4    = __attribute__((ext_vector_type(4))) _Float16;
using h8    = __attribute__((ext_vector_type(8))) _Float16;
using f32x4 = __attribute__((ext_vector_type(4))) float;

// acc: 64 slots x 32 floats: 0=con 1=gx 2=gy 3=cb 4=cr 5=ssim_rgb 6=ssim_ir
// ws layout: [0,8KB) acc slots; [8KB,10KB) 64-lane weight-frag table
#define NSLOT 64
#define SLOT_F 32
#define WTAB_OFF 8192

__global__ __launch_bounds__(256) void k_zero(float* __restrict__ acc) {
  int i = threadIdx.x;
  *(f4*)&acc[i*8]     = f4{0,0,0,0};
  *(f4*)&acc[i*8 + 4] = f4{0,0,0,0};
  // weight fragment table: lane l holds Wh/Wv B-frags for MFMA convs
  // w(d)=exp(-d^2/4.5)/3.759232795; Wh[k][x]=g[k-x-3], Wv[k][y]=g[k-y]
  if (i < 64) {
    int lr = i & 15, lg = (i >> 4) & 3;
    h8 bh, bv;
    #pragma unroll
    for (int e = 0; e < 8; ++e) {
      int k = lg*8 + e;
      int jh = k - lr - 3;
      int jv = k - lr;
      float wh = 0.f, wvv = 0.f;
      if ((unsigned)jh < 11u) {
        float d = (float)(jh - 5);
        wh = exp2f(-d*d*0.32059889798f) * 0.26601255681f;
      }
      if ((unsigned)jv < 11u) {
        float d = (float)(jv - 5);
        wvv = exp2f(-d*d*0.32059889798f) * 0.26601255681f;
      }
      bh[e] = (_Float16)wh;
      bv[e] = (_Float16)wvv;
    }
    char* wt = (char*)acc + WTAB_OFF + i*32;
    *(h8*)wt        = bh;
    *(h8*)(wt + 16) = bv;
  }
}

__device__ __forceinline__ h4 cvt4(f4 v) {
  h2 lo = __builtin_bit_cast(h2, __builtin_amdgcn_cvt_pkrtz(v.x, v.y));
  h2 hi = __builtin_bit_cast(h2, __builtin_amdgcn_cvt_pkrtz(v.z, v.w));
  return h4{lo[0], lo[1], hi[0], hi[1]};
}
__device__ __forceinline__ h4 pk4(f32x4 d) {
  h2 lo = __builtin_bit_cast(h2, __builtin_amdgcn_cvt_pkrtz(d[0], d[1]));
  h2 hi = __builtin_bit_cast(h2, __builtin_amdgcn_cvt_pkrtz(d[2], d[3]));
  return h4{lo[0], lo[1], hi[0], hi[1]};
}
__device__ __forceinline__ h8 zero8() {
  return h8{(_Float16)0,(_Float16)0,(_Float16)0,(_Float16)0,
            (_Float16)0,(_Float16)0,(_Float16)0,(_Float16)0};
}

// ---- sobel geometry: tile 64x16, halo 1; LDS row stride 68 floats -------
#define R1W 68
#define R1N (18*R1W)   // 1224 floats per field

// ---- SSIM MFMA geometry (offsets in _Float16 units) ----------------------
// staged: 2 fields (A=x, B=y), 26 rows x 80 cols used, stride 88 (bank-free)
// hbT:    4 fields x 64 px x 32 k, XOR-swizzled 16B granules
#define SXW 88
#define SXH 26
#define SF_STRIDE (SXH*SXW)          // 2288 halves per field
#define HB_OFF    (2*SF_STRIDE)      // 4576
#define HB_F      (64*32)            // 2048 halves per field
#define SMEM_H    (HB_OFF + 4*HB_F)  // 12768 halves
#define SMEM_BYTES (SMEM_H*2 + 128)  // 25664 bytes (sobel needs 14688)

// ---- Phase B: horizontal conv via MFMA; wave = x-tile ---------------------
__device__ __forceinline__ void phaseB(_Float16* S, h8 bh,
                                       int lr, int lg, int xo) {
  const int px = xo + lr;
  const int sgrp = (px ^ (px >> 2)) & 3;            // bank swizzle key
  #pragma unroll
  for (int rt = 0; rt < 2; ++rt) {
    int row_s = rt*16 + lr;
    int rcl = row_s > 25 ? 25 : row_s;
    int rbase = rcl*SXW + xo + lg*8;
    h8 a = *(const h8*)&S[rbase];
    h8 b = *(const h8*)&S[SF_STRIDE + rbase];
    if (row_s > 25) { a = zero8(); b = zero8(); }
    h8 p = a*a + b*b;
    h8 q = a*b;
    f32x4 d0 = __builtin_amdgcn_mfma_f32_16x16x32_f16(
                   a, bh, f32x4{0.f,0.f,0.f,0.f}, 0, 0, 0);
    f32x4 d1 = __builtin_amdgcn_mfma_f32_16x16x32_f16(
                   b, bh, f32x4{0.f,0.f,0.f,0.f}, 0, 0, 0);
    f32x4 d2 = __builtin_amdgcn_mfma_f32_16x16x32_f16(
                   p, bh, f32x4{0.f,0.f,0.f,0.f}, 0, 0, 0);
    f32x4 d3 = __builtin_amdgcn_mfma_f32_16x16x32_f16(
                   q, bh, f32x4{0.f,0.f,0.f,0.f}, 0, 0, 0);
    int k0 = rt*16 + lg*4;
    int bb2 = k0 << 1;                              // byte in 64B row
    int sbk = ((((bb2 >> 4) ^ sgrp) << 4) | (bb2 & 15));
    int base = HB_OFF + px*32 + (sbk >> 1);
    *(h4*)&S[base + 0*HB_F] = pk4(d0);
    *(h4*)&S[base + 1*HB_F] = pk4(d1);
    *(h4*)&S[base + 2*HB_F] = pk4(d2);
    *(h4*)&S[base + 3*HB_F] = pk4(d3);
  }
}

// ---- Phase C: vertical conv via MFMA + SSIM epilogue ----------------------
__device__ __forceinline__ float phaseC(const _Float16* S, h8 bv,
                                        int lr, int lg, int xo) {
  const int pxA = xo + lr;
  const int sgrp = (pxA ^ (pxA >> 2)) & 3;
  const int gi = lg ^ sgrp;
  f32x4 dd[4];
  #pragma unroll
  for (int f = 0; f < 4; ++f) {
    h8 a = *(const h8*)&S[HB_OFF + f*HB_F + pxA*32 + gi*8];
    dd[f] = __builtin_amdgcn_mfma_f32_16x16x32_f16(
                a, bv, f32x4{0.f,0.f,0.f,0.f}, 0, 0, 0);
  }
  float ss = 0.f;
  #pragma unroll
  for (int r2 = 0; r2 < 4; ++r2) {
    float mu1 = dd[0][r2], mu2 = dd[1][r2];
    float sP  = dd[2][r2], sQ  = dd[3][r2];
    float mu12 = mu1*mu2, mss = mu1*mu1 + mu2*mu2;
    float s12 = sQ - mu12, sps = sP - mss;
    float num = (2.f*mu12 + 1e-4f)*(2.f*s12 + 9e-4f);
    float den = (mss + 1e-4f)*(sps + 9e-4f);
    ss += num * __builtin_amdgcn_rcpf(den);   // <=1ulp, ~1e-7 on ~1.0 ratio
  }
  return ss;
}

__global__ __launch_bounds__(256, 6) void k_main(
    const float* __restrict__ vis, const float* __restrict__ ir,
    const float* __restrict__ fuse, float* __restrict__ acc)
{
  __shared__ __align__(16) char smem[SMEM_BYTES];
  float* red = (float*)(smem + SMEM_H*2);   // 32 floats scratch
  const int tid = threadIdx.x;
  const int bid = blockIdx.x;
  float* aslot = acc + (bid & (NSLOT-1))*SLOT_F;

  // interleave: every 3rd block is sobel (8192 SSIM + 4096 sobel = 12288)
  const int sb = bid / 3;
  const int rm = bid - sb*3;

  if (rm < 2) {
    // ======== SSIM superblock: two stacked 64x16 tiles, pipelined ========
    const int si = sb*2 + rm;           // 0..8191
    const int z = si >> 7;              // n*4 + pair
    const int n = z >> 2, pair = z & 3;
    const int x0 = (si & 7)*64;
    const int y0a = ((si >> 3) & 15)*32;
    const int y0b = y0a + 16;
    _Float16* S = (_Float16*)smem;

    const int lr = tid & 15;          // frag row/col within 16
    const int lg = (tid >> 4) & 3;    // frag k-group
    const int wvw = tid >> 6;         // wave id 0..3
    const int xo = wvw*16;

    const float* xb;
    const float* yb;
    if (pair < 3) {
      xb = vis  + (n*3 + pair)*CH_STRIDE;
      yb = fuse + (n*3 + pair)*CH_STRIDE;
    } else {
      xb = ir   + n*IMG_STRIDE;
      yb = fuse + n*IMG_STRIDE;
    }

    // ---- Gaussian weight fragments from precomputed table ----
    h8 bh, bv;
    {
      const char* wt = (const char*)acc + WTAB_OFF + (tid & 63)*32;
      bh = *(const h8*)wt;
      bv = *(const h8*)(wt + 16);
    }

    // staging task split: 520 tasks, iters {tid, tid+256, tid+512(tid<8)}
    const int row0 = tid / 20,        k0c = tid - row0*20;
    const int i1r  = tid + 256;
    const int row1 = i1r / 20,        k1c = i1r - row1*20;

    // ---- stage tile0 (synchronous) ----
    if (pair < 3) {
      for (int i = tid; i < SXH*20; i += 256) {
        int row = i / 20, k = i - row*20;
        int gy = y0a - 5 + row, gx = x0 - 8 + 4*k;
        f4 xv = {0,0,0,0}, yv = {0,0,0,0};
        if ((unsigned)gy < IMG_H && (unsigned)gx < IMG_W) {
          int off = gy*IMG_W + gx;
          xv = *(const f4*)&xb[off];
          yv = *(const f4*)&yb[off];
        }
        int ib = row*SXW + 4*k;
        *(h4*)&S[ib]             = cvt4(xv);
        *(h4*)&S[SF_STRIDE + ib] = cvt4(yv);
      }
    } else {
      for (int i = tid; i < SXH*20; i += 256) {
        int row = i / 20, k = i - row*20;
        int gy = y0a - 5 + row, gx = x0 - 8 + 4*k;
        f4 xv = {0,0,0,0}, yv = {0,0,0,0};
        if ((unsigned)gy < IMG_H && (unsigned)gx < IMG_W) {
          int off = gy*IMG_W + gx;
          xv = *(const f4*)&xb[off];
          f4 rr = *(const f4*)&yb[off];
          f4 gg = *(const f4*)&yb[off + CH_STRIDE];
          f4 bb = *(const f4*)&yb[off + 2*CH_STRIDE];
          #pragma unroll
          for (int j = 0; j < 4; ++j)
            yv[j] = 0.2989f*rr[j] + 0.587f*gg[j] + 0.114f*bb[j];
        }
        int ib = row*SXW + 4*k;
        *(h4*)&S[ib]             = cvt4(xv);
        *(h4*)&S[SF_STRIDE + ib] = cvt4(yv);
      }
    }
    __syncthreads();                                 // bar A

    // ---- issue tile1 prefetch loads (iters 0,1) into registers ----
    f4 p0x = {0,0,0,0}, p0y = {0,0,0,0}, p1x = {0,0,0,0}, p1y = {0,0,0,0};
    f4 q0g = {0,0,0,0}, q0b = {0,0,0,0}, q1g = {0,0,0,0}, q1b = {0,0,0,0};
    {
      int gy0 = y0b - 5 + row0, gx0 = x0 - 8 + 4*k0c;
      int gy1 = y0b - 5 + row1, gx1 = x0 - 8 + 4*k1c;
      bool v0 = (unsigned)gy0 < IMG_H && (unsigned)gx0 < IMG_W;
      bool v1 = (unsigned)gy1 < IMG_H && (unsigned)gx1 < IMG_W;
      int o0 = gy0*IMG_W + gx0, o1 = gy1*IMG_W + gx1;
      if (pair < 3) {
        if (v0) { p0x = *(const f4*)&xb[o0]; p0y = *(const f4*)&yb[o0]; }
        if (v1) { p1x = *(const f4*)&xb[o1]; p1y = *(const f4*)&yb[o1]; }
      } else {
        if (v0) {
          p0x = *(const f4*)&xb[o0];
          p0y = *(const f4*)&yb[o0];
          q0g = *(const f4*)&yb[o0 + CH_STRIDE];
          q0b = *(const f4*)&yb[o0 + 2*CH_STRIDE];
        }
        if (v1) {
          p1x = *(const f4*)&xb[o1];
          p1y = *(const f4*)&yb[o1];
          q1g = *(const f4*)&yb[o1 + CH_STRIDE];
          q1b = *(const f4*)&yb[o1 + 2*CH_STRIDE];
        }
      }
    }

    phaseB(S, bh, lr, lg, xo);                       // tile0 horizontal
    __syncthreads();                                 // bar B

    // ---- commit tile1 staged data (regs -> LDS) ----
    {
      int ib0 = row0*SXW + 4*k0c;
      int ib1 = row1*SXW + 4*k1c;
      if (pair < 3) {
        *(h4*)&S[ib0]             = cvt4(p0x);
        *(h4*)&S[SF_STRIDE + ib0] = cvt4(p0y);
        *(h4*)&S[ib1]             = cvt4(p1x);
        *(h4*)&S[SF_STRIDE + ib1] = cvt4(p1y);
      } else {
        f4 l0, l1;
        #pragma unroll
        for (int j = 0; j < 4; ++j) {
          l0[j] = 0.2989f*p0y[j] + 0.587f*q0g[j] + 0.114f*q0b[j];
          l1[j] = 0.2989f*p1y[j] + 0.587f*q1g[j] + 0.114f*q1b[j];
        }
        *(h4*)&S[ib0]             = cvt4(p0x);
        *(h4*)&S[SF_STRIDE + ib0] = cvt4(l0);
        *(h4*)&S[ib1]             = cvt4(p1x);
        *(h4*)&S[SF_STRIDE + ib1] = cvt4(l1);
      }
      if (tid < 8) {                                 // iter2 tail (8 threads)
        int k2 = tid + 12;                           // row 25
        int gy2 = y0b + 20, gx2 = x0 - 8 + 4*k2;
        f4 xv = {0,0,0,0}, yv = {0,0,0,0};
        if ((unsigned)gy2 < IMG_H && (unsigned)gx2 < IMG_W) {
          int off = gy2*IMG_W + gx2;
          xv = *(const f4*)&xb[off];
          if (pair < 3) yv = *(const f4*)&yb[off];
          else {
            f4 rr = *(const f4*)&yb[off];
            f4 gg = *(const f4*)&yb[off + CH_STRIDE];
            f4 bb = *(const f4*)&yb[off + 2*CH_STRIDE];
            #pragma unroll
            for (int j = 0; j < 4; ++j)
              yv[j] = 0.2989f*rr[j] + 0.587f*gg[j] + 0.114f*bb[j];
          }
        }
        int ib2 = 25*SXW + 4*k2;
        *(h4*)&S[ib2]             = cvt4(xv);
        *(h4*)&S[SF_STRIDE + ib2] = cvt4(yv);
      }
    }

    float ss = phaseC(S, bv, lr, lg, xo);            // tile0 vertical+epilog
    __syncthreads();                                 // bar C
    phaseB(S, bh, lr, lg, xo);                       // tile1 horizontal
    __syncthreads();                                 // bar D
    ss += phaseC(S, bv, lr, lg, xo);                 // tile1 vertical+epilog

    #pragma unroll
    for (int o = 32; o > 0; o >>= 1) ss += __shfl_down(ss, o, 64);
    if ((tid & 63) == 0) atomicAdd(&aslot[(pair == 3) ? 6 : 5], ss);

  } else {
    // ===== point + sobel + color block (r5 structure, separable math) ====
    const int r = sb;                    // 0..4095
    const int x0 = (r & 7)*64;
    const int y0 = ((r >> 3) & 31)*16;
    const int n  = r >> 8;
    float* s = (float*)smem;   // 3 fields x 1224 floats (14.7 KB)
    const int ox = (tid & 15)*4;
    const int oy = tid >> 4;

    float con=0.f, gxs=0.f, gys=0.f, cbs=0.f, crs=0.f;
    float pv0[4], pv2[4], pf0[4], pf2[4], Yv[4], Yf[4];
    #pragma unroll
    for (int j = 0; j < 4; ++j) { Yv[j]=0.f; Yf[j]=0.f; }

    for (int c = 0; c < 3; ++c) {
      const float* pvb = vis  + (n*3 + c)*CH_STRIDE;
      const float* pib = ir   + (n*3 + c)*CH_STRIDE;
      const float* pfb = fuse + (n*3 + c)*CH_STRIDE;
      // interior: 3 fields x 18 rows x 16 f4 = 864 groups
      for (int i = tid; i < 864; i += 256) {
        int f = i / 288;
        int rr = i - f*288;
        int row = rr >> 4, k = rr & 15;
        int gy = y0 - 1 + row, gx = x0 + 4*k;
        f4 v = {0,0,0,0};
        const float* bp = (f == 0) ? pvb : ((f == 1) ? pib : pfb);
        if ((unsigned)gy < IMG_H) v = *(const f4*)&bp[gy*IMG_W + gx];
        float* dst = s + f*R1N + row*R1W + 1 + 4*k;
        dst[0]=v.x; dst[1]=v.y; dst[2]=v.z; dst[3]=v.w;
      }
      // edges: 3 fields x 18 rows x 2 = 108 scalars
      if (tid < 108) {
        int f = tid / 36;
        int rr = tid - f*36;
        int row = rr >> 1, side = rr & 1;
        int gy = y0 - 1 + row;
        int gx = side ? (x0 + 64) : (x0 - 1);
        float v = 0.f;
        const float* bp = (f == 0) ? pvb : ((f == 1) ? pib : pfb);
        if ((unsigned)gx < IMG_W && (unsigned)gy < IMG_H) v = bp[gy*IMG_W + gx];
        s[f*R1N + row*R1W + (side ? 65 : 0)] = v;
      }
      __syncthreads();

      // compute channel c (separable sobel from LDS)
      const float yc = (c == 0) ? 0.299f : ((c == 1) ? 0.587f : 0.114f);
      float cen[3][4], gxv[3][4], gyv[3][4];
      #pragma unroll
      for (int t = 0; t < 3; ++t) {
        const float* sf = s + t*R1N + oy*R1W + ox;
        f4 a0 = *(const f4*)&sf[0];
        f2 b0 = *(const f2*)&sf[4];
        f4 a1 = *(const f4*)&sf[R1W];
        f2 b1 = *(const f2*)&sf[R1W + 4];
        f4 a2 = *(const f4*)&sf[2*R1W];
        f2 b2 = *(const f2*)&sf[2*R1W + 4];
        float r0[6] = {a0.x,a0.y,a0.z,a0.w,b0.x,b0.y};
        float r1[6] = {a1.x,a1.y,a1.z,a1.w,b1.x,b1.y};
        float r2[6] = {a2.x,a2.y,a2.z,a2.w,b2.x,b2.y};
        float ty[6], dy[6];
        #pragma unroll
        for (int x = 0; x < 6; ++x) {
          ty[x] = r0[x] + 2.f*r1[x] + r2[x];   // smooth_y
          dy[x] = r0[x] - r2[x];               // diff_y
        }
        #pragma unroll
        for (int j = 0; j < 4; ++j) {
          gxv[t][j] = ty[j+2] - ty[j];                    // diff_x(smooth_y)
          gyv[t][j] = dy[j] + 2.f*dy[j+1] + dy[j+2];      // smooth_x(diff_y)
          cen[t][j] = r1[j+1];
        }
      }
      #pragma unroll
      for (int j = 0; j < 4; ++j) {
        con += fabsf(cen[2][j] - fmaxf(cen[0][j], cen[1][j]));
        gxs += fabsf(gxv[2][j] - fmaxf(gxv[0][j], gxv[1][j]));
        gys += fabsf(gyv[2][j] - fmaxf(gyv[0][j], gyv[1][j]));
        Yv[j] += yc*cen[0][j];
        Yf[j] += yc*cen[2][j];
        if (c == 0) { pv0[j] = cen[0][j]; pf0[j] = cen[2][j]; }
        if (c == 2) { pv2[j] = cen[0][j]; pf2[j] = cen[2][j]; }
      }
      __syncthreads();   // WAR guard before restaging
    }

    #pragma unroll
    for (int j = 0; j < 4; ++j) {
      crs += fabsf(0.713f*((pf0[j]-Yf[j]) - (pv0[j]-Yv[j])));
      cbs += fabsf(0.564f*((pf2[j]-Yf[j]) - (pv2[j]-Yv[j])));
    }

    // wave reduce 5 sums -> LDS -> 1 barrier -> 5 atomics
    float sums[5] = {con, gxs, gys, cbs, crs};
    const int lane = tid & 63, wvw2 = tid >> 6;
    #pragma unroll
    for (int i2 = 0; i2 < 5; ++i2) {
      float v = sums[i2];
      #pragma unroll
      for (int o = 32; o > 0; o >>= 1) v += __shfl_down(v, o, 64);
      if (lane == 0) red[wvw2*5 + i2] = v;
    }
    __syncthreads();
    if (tid < 5)
      atomicAdd(&aslot[tid], red[tid] + red[5+tid] + red[10+tid] + red[15+tid]);
  }
}

// ---------------- final combine: one wave over 64 slots -------------------
__global__ __launch_bounds__(64) void k_final(
    const float* __restrict__ acc, float* __restrict__ out)
{
  int lane = threadIdx.x;
  float s[7];
  #pragma unroll
  for (int c = 0; c < 7; ++c) {
    float x = acc[lane*SLOT_F + c];
    #pragma unroll
    for (int o = 32; o > 0; o >>= 1) x += __shfl_down(x, o, 64);
    s[c] = x;
  }
  if (lane == 0) {
    const float N3 = 16.f*3.f*512.f*512.f;
    const float N1 = 16.f*512.f*512.f;
    float con_loss  = s[0] / N3;
    float grad_loss = 0.5f*(s[1]/N3) + 0.5f*(s[2]/N3);
    float color_loss = s[3]/N1 + s[4]/N1;
    float ssim_loss = 1.f - (s[5]/N3 + s[6]/N1)*0.5f;
    out[0] = 0.5f*con_loss + 0.2f*grad_loss + color_loss + 0.1f*ssim_loss;
  }
}

extern "C" void kernel_launch(void* const* d_in, const int* in_sizes, int n_in,
                              void* d_out, int out_size, void* d_ws, size_t ws_size,
                              hipStream_t stream) {
  (void)in_sizes; (void)n_in; (void)out_size; (void)ws_size;
  const float* vis  = (const float*)d_in[0];
  const float* ir   = (const float*)d_in[1];
  const float* fuse = (const float*)d_in[2];
  float* out = (float*)d_out;
  float* acc = (float*)d_ws;   // 8 KB slots + 2 KB weight table

  k_zero<<<dim3(1,1,1), dim3(256,1,1), 0, stream>>>(acc);
  k_main<<<dim3(12288,1,1), dim3(256,1,1), 0, stream>>>(vis, ir, fuse, acc);
  k_final<<<dim3(1,1,1), dim3(64,1,1), 0, stream>>>(acc, out);
}